// Round 1
// baseline (230.919 us; speedup 1.0000x reference)
//
#include <hip/hip_runtime.h>
#include <math.h>
#include <string.h>

#define CDIM 64
#define LDSW 72   // row stride in bf16 elems (144 B): b128 frag reads measured conflict-free
#define DEG  5    // Chebyshev tail on [1,7.5] ~5.6e-3; Paterson-Stockmeyer s=2 -> 3 matmuls

struct Coefs { float a[DEG + 1]; float cc; float inv_h; };

typedef __attribute__((ext_vector_type(8)))  short short8;    // 8 bf16 = 4 VGPRs (MFMA A/B frag)
typedef __attribute__((ext_vector_type(16))) float floatx16;  // MFMA C/D

// Row-major hi/lo store of one fp32 as two bf16 (truncation split).
// Write pattern per instruction: half-wave writes 32 consecutive u16 of row q,
// other half row q+4 -> 32 disjoint banks, in-dword lane merge: 0 conflicts (measured R2).
__device__ __forceinline__ void st_hilo(unsigned short* __restrict__ Dh,
                                        unsigned short* __restrict__ Dl,
                                        int idx, float x) {
  const unsigned u = __builtin_bit_cast(unsigned, x);
  const float h = __builtin_bit_cast(float, u & 0xFFFF0000u);
  const float l = x - h;                       // exact
  const unsigned ul = __builtin_bit_cast(unsigned, l);
  Dh[idx] = (unsigned short)(u >> 16);
  Dl[idx] = (unsigned short)(ul >> 16);
}

__device__ __forceinline__ float bf16_to_f(short s) {
  return __builtin_bit_cast(float, ((unsigned)(unsigned short)s) << 16);
}

struct Frags { short8 h[4]; short8 l[4]; };    // 4 K-slabs of hi+lo fragments

__device__ __forceinline__ void load_frags(const unsigned short* __restrict__ Ph,
                                           const unsigned short* __restrict__ Pl,
                                           int row, int ko, Frags* f) {
#pragma unroll
  for (int kk = 0; kk < 4; ++kk) {
    f->h[kk] = *(const short8*)(Ph + row * LDSW + kk * 16 + ko);
    f->l[kk] = *(const short8*)(Pl + row * LDSW + kk * 16 + ko);
  }
}

// 32x32 tile product, compensated split on TWO acc chains (hh) and (hl+lh):
// saves 16 VGPRs vs 3 chains; the 8-deep c2 dependency is hidden at 4 blocks/CU.
__device__ __forceinline__ floatx16 mm_frags(const Frags& a, const Frags& b) {
  floatx16 c1, c2;
#pragma unroll
  for (int i = 0; i < 16; ++i) { c1[i] = 0.0f; c2[i] = 0.0f; }
#pragma unroll
  for (int kk = 0; kk < 4; ++kk) {
    c1 = __builtin_amdgcn_mfma_f32_32x32x16_bf16(a.h[kk], b.h[kk], c1, 0, 0, 0);
    c2 = __builtin_amdgcn_mfma_f32_32x32x16_bf16(a.h[kk], b.l[kk], c2, 0, 0, 0);
    c2 = __builtin_amdgcn_mfma_f32_32x32x16_bf16(a.l[kk], b.h[kk], c2, 0, 0, 0);
  }
#pragma unroll
  for (int i = 0; i < 16; ++i) c1[i] += c2[i];
  return c1;
}

// Q0 = a4 I + a5 M1 derived IN-REGISTER from M1's A-operand fragments:
// same rows (arow), same k-slices -> no LDS buffer, no staging stores, no frag loads.
// Reconstruct t = hi+lo in f32 (2^-16 rel), scale, re-split. Error << 2^-8 budget.
__device__ __forceinline__ void derive_q0(const Frags& fm1, Frags* fq,
                                          float a5, float a4, int arow, int ko) {
#pragma unroll
  for (int kk = 0; kk < 4; ++kk) {
#pragma unroll
    for (int j = 0; j < 8; ++j) {
      const float t = bf16_to_f(fm1.h[kk][j]) + bf16_to_f(fm1.l[kk][j]);
      float q = a5 * t;
      if (arow == kk * 16 + ko + j) q += a4;   // diagonal term
      const unsigned u = __builtin_bit_cast(unsigned, q);
      const float qh = __builtin_bit_cast(float, u & 0xFFFF0000u);
      const unsigned ul = __builtin_bit_cast(unsigned, q - qh);
      fq->h[kk][j] = (short)(unsigned short)(u >> 16);
      fq->l[kk][j] = (short)(unsigned short)(ul >> 16);
    }
  }
}

__global__ void __launch_bounds__(256, 4)
logm_kernel(const float* __restrict__ X, float* __restrict__ Y, Coefs cf) {
  // Buffers: A = M1 then Q1, C = M2.  4 x 9216 B = 36.9 KB -> 4 blocks/CU (was 2).
  __shared__ __align__(16) unsigned short Ah[CDIM * LDSW], Al[CDIM * LDSW];
  __shared__ __align__(16) unsigned short Ch[CDIM * LDSW], Cl[CDIM * LDSW];

  const int tid  = threadIdx.x;
  const int lane = tid & 63;
  const int w    = tid >> 6;
  const int m    = blockIdx.x;

  const float* __restrict__ Xm = X + (size_t)m * (CDIM * CDIM);
  float* __restrict__ Ym       = Y + (size_t)m * (CDIM * CDIM);

  const int R    = (w >> 1) * 32;
  const int Cc   = (w & 1) * 32;
  const int l31  = lane & 31;
  const int half = lane >> 5;
  const int arow = R + l31;
  const int brow = Cc + l31;
  const int ko   = half * 8;
  const int col  = Cc + l31;
  int rows[16];  // C/D layout: row = (r&3) + 8*(r>>2) + 4*half  [verified m74/m101]
#pragma unroll
  for (int r = 0; r < 16; ++r) rows[r] = R + (r & 3) + 8 * (r >> 2) + 4 * half;

  // ---- stage: load X once in C-layout (coalesced 2x128B per instr), keep rM1 in regs,
  //      write M1 -> A only (Q0 no longer staged; derived in-register in mm1) ----
  float rM1[16];
#pragma unroll
  for (int r = 0; r < 16; ++r) {
    float x = Xm[rows[r] * CDIM + col];
    if (rows[r] == col) x -= cf.cc;
    const float t = x * cf.inv_h;
    rM1[r] = t;
    st_hilo(Ah, Al, rows[r] * LDSW + col, t);
  }
  __syncthreads();

  // ---- mm1: M2 = M1*M1 -> C ; derive Q0 frags from fa while fa is live ----
  Frags fa, fb;
  load_frags(Ah, Al, arow, ko, &fa);
  if (R == Cc) fb = fa; else load_frags(Ah, Al, brow, ko, &fb);  // wave-uniform branch
  floatx16 accM2 = mm_frags(fa, fb);
  Frags fq;
  derive_q0(fa, &fq, cf.a[5], cf.a[4], arow, ko);
#pragma unroll
  for (int r = 0; r < 16; ++r) st_hilo(Ch, Cl, rows[r] * LDSW + col, accM2[r]);
  __syncthreads();   // all A (M1) reads complete; C (M2) visible

  // ---- mm2: Q1 = Q0*M2 + (a2 I + a3 M1) -> A  (no wave reads A in this phase) ----
  Frags fm2;
  load_frags(Ch, Cl, brow, ko, &fm2);    // B-operand M2 via bitwise symmetry; cached for mm3
  floatx16 accQ = mm_frags(fq, fm2);
#pragma unroll
  for (int r = 0; r < 16; ++r) {
    float p = accQ[r] + cf.a[3] * rM1[r];
    if (rows[r] == col) p += cf.a[2];
    st_hilo(Ah, Al, rows[r] * LDSW + col, p);
  }
  __syncthreads();

  // ---- mm3: out = Q1*M2 + (a0 I + a1 M1) -> global (2x128B coalesced per instr) ----
  Frags fq1;
  load_frags(Ah, Al, arow, ko, &fq1);
  floatx16 accF = mm_frags(fq1, fm2);
#pragma unroll
  for (int r = 0; r < 16; ++r) {
    float p = accF[r] + cf.a[1] * rM1[r];
    if (rows[r] == col) p += cf.a[0];
    Ym[rows[r] * CDIM + col] = p;
  }
}

extern "C" void kernel_launch(void* const* d_in, const int* in_sizes, int n_in,
                              void* d_out, int out_size, void* d_ws, size_t ws_size,
                              hipStream_t stream) {
  const float* X = (const float*)d_in[0];
  float* Y = (float*)d_out;
  const int nmat = in_sizes[0] / (CDIM * CDIM);

  // Chebyshev coefficients of log on [lo,hi] -> monomial basis in t=(x-cc)/hh.
  // Analytic: log(cc+hh*t) = log(A) - 2*sum_k z^k/k T_k(t),  z=(-cc+sqrt(cc^2-hh^2))/hh
  Coefs cf;
  {
    const double lo = 1.0, hi = 7.5;
    const double cc = 0.5 * (lo + hi), hh = 0.5 * (hi - lo);
    const double s  = sqrt(cc * cc - hh * hh);
    const double z  = (-cc + s) / hh;
    const double A  = 0.5 * (cc + s);
    double cheb[DEG + 1];
    cheb[0] = log(A);
    double zp = 1.0;
    for (int k = 1; k <= DEG; ++k) { zp *= z; cheb[k] = -2.0 * zp / (double)k; }
    double mono[DEG + 1], Tprev[DEG + 1], Tcur[DEG + 1];
    memset(mono, 0, sizeof(mono));
    memset(Tprev, 0, sizeof(Tprev));
    memset(Tcur, 0, sizeof(Tcur));
    Tprev[0] = 1.0; mono[0] += cheb[0];
    Tcur[1]  = 1.0; mono[1] += cheb[1];
    for (int k = 2; k <= DEG; ++k) {
      double Tn[DEG + 1];
      memset(Tn, 0, sizeof(Tn));
      for (int j = 0; j <= k; ++j) {
        double v = -Tprev[j];
        if (j > 0) v += 2.0 * Tcur[j - 1];
        Tn[j] = v;
      }
      for (int j = 0; j <= k; ++j) mono[j] += cheb[k] * Tn[j];
      for (int j = 0; j <= DEG; ++j) { Tprev[j] = Tcur[j]; Tcur[j] = Tn[j]; }
    }
    for (int i = 0; i <= DEG; ++i) cf.a[i] = (float)mono[i];
    cf.cc = (float)cc; cf.inv_h = (float)(1.0 / hh);
  }

  dim3 grid(nmat), block(256);
  hipLaunchKernelGGL(logm_kernel, grid, block, 0, stream, X, Y, cf);
}

// Round 2
// 184.148 us; speedup vs baseline: 1.2540x; 1.2540x over previous
//
#include <hip/hip_runtime.h>
#include <math.h>
#include <string.h>

#define CDIM 64
#define LDSW 72   // row stride in bf16 elems (144 B): b128 frag reads measured conflict-free
#define DEG  5    // Chebyshev tail on [1,7.5] ~5.6e-3; Paterson-Stockmeyer s=2 -> 3 matmuls

struct Coefs { float a[DEG + 1]; float cc; float inv_h; };

typedef __attribute__((ext_vector_type(8)))  short short8;    // 8 bf16 = 4 VGPRs (MFMA A/B frag)
typedef __attribute__((ext_vector_type(16))) float floatx16;  // MFMA C/D

// Row-major hi/lo store of one fp32 as two bf16 (truncation split).
// Write pattern per instruction: half-wave writes 32 consecutive u16 of row q,
// other half row q+4 -> 32 disjoint banks, in-dword lane merge: 0 conflicts (measured R2).
__device__ __forceinline__ void st_hilo(unsigned short* __restrict__ Dh,
                                        unsigned short* __restrict__ Dl,
                                        int idx, float x) {
  const unsigned u = __builtin_bit_cast(unsigned, x);
  const float h = __builtin_bit_cast(float, u & 0xFFFF0000u);
  const float l = x - h;                       // exact
  const unsigned ul = __builtin_bit_cast(unsigned, l);
  Dh[idx] = (unsigned short)(u >> 16);
  Dl[idx] = (unsigned short)(ul >> 16);
}

// Scalar hi/lo read back to f32 (~2^-17 rel error vs stored value).
__device__ __forceinline__ float ld_hilo(const unsigned short* __restrict__ Ph,
                                         const unsigned short* __restrict__ Pl,
                                         int idx) {
  const float h = __builtin_bit_cast(float, ((unsigned)Ph[idx]) << 16);
  const float l = __builtin_bit_cast(float, ((unsigned)Pl[idx]) << 16);
  return h + l;
}

struct Frags { short8 h[4]; short8 l[4]; };    // 4 K-slabs of hi+lo fragments

__device__ __forceinline__ void load_frags(const unsigned short* __restrict__ Ph,
                                           const unsigned short* __restrict__ Pl,
                                           int row, int ko, Frags* f) {
#pragma unroll
  for (int kk = 0; kk < 4; ++kk) {
    f->h[kk] = *(const short8*)(Ph + row * LDSW + kk * 16 + ko);
    f->l[kk] = *(const short8*)(Pl + row * LDSW + kk * 16 + ko);
  }
}

// 32x32 tile product, compensated split on TWO acc chains (hh) and (hl+lh):
// saves 16 VGPRs vs 3 chains; the 8-deep c2 dependency is hidden at 4 blocks/CU.
__device__ __forceinline__ floatx16 mm_frags(const Frags& a, const Frags& b) {
  floatx16 c1, c2;
#pragma unroll
  for (int i = 0; i < 16; ++i) { c1[i] = 0.0f; c2[i] = 0.0f; }
#pragma unroll
  for (int kk = 0; kk < 4; ++kk) {
    c1 = __builtin_amdgcn_mfma_f32_32x32x16_bf16(a.h[kk], b.h[kk], c1, 0, 0, 0);
    c2 = __builtin_amdgcn_mfma_f32_32x32x16_bf16(a.h[kk], b.l[kk], c2, 0, 0, 0);
    c2 = __builtin_amdgcn_mfma_f32_32x32x16_bf16(a.l[kk], b.h[kk], c2, 0, 0, 0);
  }
#pragma unroll
  for (int i = 0; i < 16; ++i) c1[i] += c2[i];
  return c1;
}

__global__ void __launch_bounds__(256, 4)
logm_kernel(const float* __restrict__ X, float* __restrict__ Y, Coefs cf) {
  // Buffers: A = M1 (never overwritten), C = M2 then Q1.
  // 4 x 9216 B = 36.9 KB -> 4 blocks/CU.
  // Register diet vs R1 (which spilled ~150 live regs against the 128 cap):
  //   - no Q0 frags: Q0*M2 = a5*(M1*M2) + a4*M2 via bilinearity; a4*M2 uses accM2
  //     still live in AGPRs from mm1 (exact f32, free).
  //   - no rM1[16]: M1 epilogue terms re-read as scalar hi/lo from A.
  // Peak live: 2 Frags (64) + accs (48 AGPR) + misc ~ 120 <= 128.
  __shared__ __align__(16) unsigned short Ah[CDIM * LDSW], Al[CDIM * LDSW];
  __shared__ __align__(16) unsigned short Ch[CDIM * LDSW], Cl[CDIM * LDSW];

  const int tid  = threadIdx.x;
  const int lane = tid & 63;
  const int w    = tid >> 6;
  const int m    = blockIdx.x;

  const float* __restrict__ Xm = X + (size_t)m * (CDIM * CDIM);
  float* __restrict__ Ym       = Y + (size_t)m * (CDIM * CDIM);

  const int R    = (w >> 1) * 32;
  const int Cc   = (w & 1) * 32;
  const int l31  = lane & 31;
  const int half = lane >> 5;
  const int arow = R + l31;
  const int brow = Cc + l31;
  const int ko   = half * 8;
  const int col  = Cc + l31;
  int rows[16];  // C/D layout: row = (r&3) + 8*(r>>2) + 4*half  [verified m74/m101]
#pragma unroll
  for (int r = 0; r < 16; ++r) rows[r] = R + (r & 3) + 8 * (r >> 2) + 4 * half;

  // ---- stage: load X once in C-layout (coalesced 2x128B per instr), M1 -> A ----
#pragma unroll
  for (int r = 0; r < 16; ++r) {
    float x = Xm[rows[r] * CDIM + col];
    if (rows[r] == col) x -= cf.cc;
    st_hilo(Ah, Al, rows[r] * LDSW + col, x * cf.inv_h);
  }
  __syncthreads();

  // ---- mm1: M2 = M1*M1 -> C; keep accM2 (f32, AGPRs) for the a4*M2 term ----
  Frags fa, fb;
  load_frags(Ah, Al, arow, ko, &fa);
  if (R == Cc) fb = fa; else load_frags(Ah, Al, brow, ko, &fb);  // wave-uniform branch
  floatx16 accM2 = mm_frags(fa, fb);
#pragma unroll
  for (int r = 0; r < 16; ++r) st_hilo(Ch, Cl, rows[r] * LDSW + col, accM2[r]);
  __syncthreads();

  // ---- mm2: T = M1*M2; Q1 = a5*T + a4*accM2 + a3*M1 + a2*I -> C (over M2) ----
  Frags fm1, fm2;
  load_frags(Ah, Al, arow, ko, &fm1);    // M1 A-rows (A intact; compiler may CSE with fa)
  load_frags(Ch, Cl, brow, ko, &fm2);    // M2 B-operand via symmetry; kept in regs for mm3
  floatx16 accT = mm_frags(fm1, fm2);
  __syncthreads();                       // all C (M2) reads complete before overwrite
#pragma unroll
  for (int r = 0; r < 16; ++r) {
    const int idx = rows[r] * LDSW + col;
    float q = cf.a[5] * accT[r] + cf.a[4] * accM2[r] + cf.a[3] * ld_hilo(Ah, Al, idx);
    if (rows[r] == col) q += cf.a[2];
    st_hilo(Ch, Cl, idx, q);
  }
  __syncthreads();

  // ---- mm3: out = Q1*M2 + a1*M1 + a0*I -> global (2x128B coalesced per instr) ----
  Frags fq1;
  load_frags(Ch, Cl, arow, ko, &fq1);
  floatx16 accF = mm_frags(fq1, fm2);
#pragma unroll
  for (int r = 0; r < 16; ++r) {
    float p = accF[r] + cf.a[1] * ld_hilo(Ah, Al, rows[r] * LDSW + col);
    if (rows[r] == col) p += cf.a[0];
    Ym[rows[r] * CDIM + col] = p;
  }
}

extern "C" void kernel_launch(void* const* d_in, const int* in_sizes, int n_in,
                              void* d_out, int out_size, void* d_ws, size_t ws_size,
                              hipStream_t stream) {
  const float* X = (const float*)d_in[0];
  float* Y = (float*)d_out;
  const int nmat = in_sizes[0] / (CDIM * CDIM);

  // Chebyshev coefficients of log on [lo,hi] -> monomial basis in t=(x-cc)/hh.
  // Analytic: log(cc+hh*t) = log(A) - 2*sum_k z^k/k T_k(t),  z=(-cc+sqrt(cc^2-hh^2))/hh
  Coefs cf;
  {
    const double lo = 1.0, hi = 7.5;
    const double cc = 0.5 * (lo + hi), hh = 0.5 * (hi - lo);
    const double s  = sqrt(cc * cc - hh * hh);
    const double z  = (-cc + s) / hh;
    const double A  = 0.5 * (cc + s);
    double cheb[DEG + 1];
    cheb[0] = log(A);
    double zp = 1.0;
    for (int k = 1; k <= DEG; ++k) { zp *= z; cheb[k] = -2.0 * zp / (double)k; }
    double mono[DEG + 1], Tprev[DEG + 1], Tcur[DEG + 1];
    memset(mono, 0, sizeof(mono));
    memset(Tprev, 0, sizeof(Tprev));
    memset(Tcur, 0, sizeof(Tcur));
    Tprev[0] = 1.0; mono[0] += cheb[0];
    Tcur[1]  = 1.0; mono[1] += cheb[1];
    for (int k = 2; k <= DEG; ++k) {
      double Tn[DEG + 1];
      memset(Tn, 0, sizeof(Tn));
      for (int j = 0; j <= k; ++j) {
        double v = -Tprev[j];
        if (j > 0) v += 2.0 * Tcur[j - 1];
        Tn[j] = v;
      }
      for (int j = 0; j <= k; ++j) mono[j] += cheb[k] * Tn[j];
      for (int j = 0; j <= DEG; ++j) { Tprev[j] = Tcur[j]; Tcur[j] = Tn[j]; }
    }
    for (int i = 0; i <= DEG; ++i) cf.a[i] = (float)mono[i];
    cf.cc = (float)cc; cf.inv_h = (float)(1.0 / hh);
  }

  dim3 grid(nmat), block(256);
  hipLaunchKernelGGL(logm_kernel, grid, block, 0, stream, X, Y, cf);
}